// Round 5
// baseline (2536.213 us; speedup 1.0000x reference)
//
#include <hip/hip_runtime.h>
#include <hip/hip_bf16.h>
#include <math.h>

#define N_OBJ 4096
#define IN_DIM 1024
#define EMB_D 200
#define HID 1024
#define NCLS 151
#define NCPAD 160       // NCLS padded to 10 MFMA col-frags
#define IN_SZ 1224      // IN_DIM + EMB_D
#define NEMB 152        // NCLS + 1 embedding rows
#define R5 5120         // px(1024) + iou(3072) + f(1024) pre-activation rows
#define RH 4096         // h-dependent rows (iou 3072 + f 1024)
#define MAXLVL 32

typedef __attribute__((ext_vector_type(8))) short bf16x8;
typedef __attribute__((ext_vector_type(4))) float f32x4;

__device__ __forceinline__ float sigf(float x) { return 1.f / (1.f + expf(-x)); }

// split fp32 into hi+lo bf16 (RNE both stages); hi+lo carries ~18 mantissa bits
__device__ __forceinline__ void split2(float x, ushort& hi, ushort& lo) {
    unsigned u = __float_as_uint(x);
    unsigned r = u + 0x7FFFu + ((u >> 16) & 1u);
    hi = (ushort)(r >> 16);
    float rem = x - __uint_as_float(r & 0xFFFF0000u);
    unsigned u2 = __float_as_uint(rem);
    unsigned r2 = u2 + 0x7FFFu + ((u2 >> 16) & 1u);
    lo = (ushort)(r2 >> 16);
}

// ---------------------------------------------------------------------------
// Kernel 1: depth per step, bucket steps by level; also zero zpad.
// ---------------------------------------------------------------------------
__global__ __launch_bounds__(1024)
void build_levels(const int* __restrict__ parent_pos,
                  int* __restrict__ level_nodes,
                  int* __restrict__ level_start,
                  ushort* __restrict__ zpad)
{
    __shared__ int dep[N_OBJ];
    __shared__ int par[N_OBJ];
    __shared__ int cnt[MAXLVL];
    __shared__ int offs[MAXLVL];
    __shared__ int base[MAXLVL + 1];
    __shared__ int done;
    const int tid = threadIdx.x;

    if (tid < 1024) zpad[tid] = 0;

    for (int t = tid; t < N_OBJ; t += 1024) {
        int p = parent_pos[t];
        par[t] = p;
        dep[t] = (p < 0) ? 0 : -1;
    }
    for (int l = tid; l < MAXLVL; l += 1024) { cnt[l] = 0; offs[l] = 0; }
    __syncthreads();

    for (int it = 0; it < 64; ++it) {
        if (tid == 0) done = 1;
        __syncthreads();
        for (int t = tid; t < N_OBJ; t += 1024) {
            if (dep[t] < 0) {
                int dp = dep[par[t]];
                if (dp >= 0) dep[t] = dp + 1;
                else done = 0;
            }
        }
        __syncthreads();
        int d = done;
        __syncthreads();
        if (d) break;
    }

    for (int t = tid; t < N_OBJ; t += 1024) {
        int d = dep[t];
        if (d < 0 || d >= MAXLVL) d = MAXLVL - 1;  // safety clamp
        dep[t] = d;
        atomicAdd(&cnt[d], 1);
    }
    __syncthreads();
    if (tid == 0) {
        base[0] = 0;
        for (int l = 0; l < MAXLVL; ++l) base[l + 1] = base[l] + cnt[l];
    }
    __syncthreads();
    for (int t = tid; t < N_OBJ; t += 1024) {
        int d = dep[t];
        int pos = base[d] + atomicAdd(&offs[d], 1);
        level_nodes[pos] = t;
    }
    for (int l = tid; l <= MAXLVL; l += 1024) level_start[l] = base[l];
}

// ---------------------------------------------------------------------------
// Kernel 2: Xemb[e][r] = W_row_r[:, 1024:1224] @ embed_W[e] + (all biases)
// ---------------------------------------------------------------------------
__global__ __launch_bounds__(256)
void xemb_kernel(const float* __restrict__ embed_W,
                 const float* __restrict__ W_px,
                 const float* __restrict__ W_ioux,
                 const float* __restrict__ W_fx,
                 const float* __restrict__ b_px,
                 const float* __restrict__ b_ioux,
                 const float* __restrict__ b_iouh,
                 const float* __restrict__ b_fx,
                 const float* __restrict__ b_fh,
                 float* __restrict__ Xemb)
{
    __shared__ float e_s[EMB_D];
    const int e = blockIdx.x;
    const int r = blockIdx.y * 256 + threadIdx.x;
    for (int k = threadIdx.x; k < EMB_D; k += 256) e_s[k] = embed_W[(size_t)e * EMB_D + k];
    __syncthreads();

    const float* wrow;
    float bias;
    if (r < HID) {
        wrow = W_px + (size_t)r * IN_SZ;
        bias = b_px[r];
    } else if (r < 4 * HID) {
        wrow = W_ioux + (size_t)(r - HID) * IN_SZ;
        bias = b_ioux[r - HID] + b_iouh[r - HID];
    } else {
        wrow = W_fx + (size_t)(r - 4 * HID) * IN_SZ;
        bias = b_fx[r - 4 * HID] + b_fh[r - 4 * HID];
    }

    float s = bias;
    for (int k = 0; k < EMB_D; ++k) s += wrow[IN_DIM + k] * e_s[k];
    Xemb[(size_t)e * R5 + r] = s;
}

// ---------------------------------------------------------------------------
// One-time split-conversion kernels (fp32 -> hi/lo bf16 pairs)
// ---------------------------------------------------------------------------
__global__ __launch_bounds__(256)
void convert_wh(const float* __restrict__ W_iouh, const float* __restrict__ W_fh,
                ushort* __restrict__ Whh, ushort* __restrict__ Whl)
{
    const int idx = (blockIdx.x * 256 + threadIdx.x) * 4;
    const int row = idx >> 10, k = idx & 1023;
    const float* src = (row < 3 * HID) ? (W_iouh + (size_t)row * HID + k)
                                       : (W_fh + (size_t)(row - 3 * HID) * HID + k);
    float4 v = *(const float4*)src;
    ushort4 hi, lo;
    split2(v.x, hi.x, lo.x); split2(v.y, hi.y, lo.y);
    split2(v.z, hi.z, lo.z); split2(v.w, hi.w, lo.w);
    *(ushort4*)(Whh + (size_t)row * HID + k) = hi;
    *(ushort4*)(Whl + (size_t)row * HID + k) = lo;
}

__global__ __launch_bounds__(256)
void convert_wx(const float* __restrict__ W_px, const float* __restrict__ W_ioux,
                const float* __restrict__ W_fx,
                ushort* __restrict__ Wxh, ushort* __restrict__ Wxl)
{
    const int idx = (blockIdx.x * 256 + threadIdx.x) * 4;
    const int row = idx >> 10, k = idx & 1023;
    const float* src;
    if (row < HID)          src = W_px   + (size_t)row * IN_SZ + k;
    else if (row < 4 * HID) src = W_ioux + (size_t)(row - HID) * IN_SZ + k;
    else                    src = W_fx   + (size_t)(row - 4 * HID) * IN_SZ + k;
    float4 v = *(const float4*)src;
    ushort4 hi, lo;
    split2(v.x, hi.x, lo.x); split2(v.y, hi.y, lo.y);
    split2(v.z, hi.z, lo.z); split2(v.w, hi.w, lo.w);
    *(ushort4*)(Wxh + (size_t)row * IN_DIM + k) = hi;
    *(ushort4*)(Wxl + (size_t)row * IN_DIM + k) = lo;
}

__global__ __launch_bounds__(256)
void convert_f(const float* __restrict__ features, const int* __restrict__ proc_order,
               ushort* __restrict__ Fh, ushort* __restrict__ Fl)
{
    const int idx = (blockIdx.x * 256 + threadIdx.x) * 4;
    const int t = idx >> 10, k = idx & 1023;
    const float* src = features + (size_t)proc_order[t] * IN_DIM + k;
    float4 v = *(const float4*)src;
    ushort4 hi, lo;
    split2(v.x, hi.x, lo.x); split2(v.y, hi.y, lo.y);
    split2(v.z, hi.z, lo.z); split2(v.w, hi.w, lo.w);
    *(ushort4*)(Fh + (size_t)t * IN_DIM + k) = hi;
    *(ushort4*)(Fl + (size_t)t * IN_DIM + k) = lo;
}

// W_out -> padded [NCPAD][HID] split pair (rows >= NCLS zeroed)
__global__ __launch_bounds__(256)
void convert_wout(const float* __restrict__ W_out,
                  ushort* __restrict__ Woh, ushort* __restrict__ Wol)
{
    const int idx = (blockIdx.x * 256 + threadIdx.x) * 4;
    const int row = idx >> 10, k = idx & 1023;
    float4 v = make_float4(0.f, 0.f, 0.f, 0.f);
    if (row < NCLS) v = *(const float4*)(W_out + (size_t)row * HID + k);
    ushort4 hi, lo;
    split2(v.x, hi.x, lo.x); split2(v.y, hi.y, lo.y);
    split2(v.z, hi.z, lo.z); split2(v.w, hi.w, lo.w);
    *(ushort4*)(Woh + (size_t)row * HID + k) = hi;
    *(ushort4*)(Wol + (size_t)row * HID + k) = lo;
}

// ---------------------------------------------------------------------------
// Kernel 3 (ONCE): x-part GEMM via split-bf16 MFMA, coalesced LDS epilogue.
// ---------------------------------------------------------------------------
__global__ __launch_bounds__(256)
void xgemm_mfma(const ushort* __restrict__ Fh, const ushort* __restrict__ Fl,
                const ushort* __restrict__ Wxh, const ushort* __restrict__ Wxl,
                float* __restrict__ Hbuf)
{
    const int bid = blockIdx.x;
    const int sup = bid >> 6, within = bid & 63;
    const int bm = (sup & 3) * 8 + (within & 7);
    const int bn = (sup >> 2) * 8 + (within >> 3);

    __shared__ __align__(16) ushort smem[4 * 128 * 72];   // 73728 B
    ushort* Ah = smem;
    ushort* Al = smem + 128 * 72;
    ushort* Bh = smem + 2 * 128 * 72;
    ushort* Bl = smem + 3 * 128 * 72;

    const int tid = threadIdx.x;
    const int lane = tid & 63;
    const int wid = tid >> 6;
    const int wm = wid & 1, wn = wid >> 1;

    const int srow = tid >> 1, skq = tid & 1;
    const ushort* gAh = Fh  + (size_t)(bm * 128 + srow) * IN_DIM + skq * 32;
    const ushort* gAl = Fl  + (size_t)(bm * 128 + srow) * IN_DIM + skq * 32;
    const ushort* gBh = Wxh + (size_t)(bn * 128 + srow) * IN_DIM + skq * 32;
    const ushort* gBl = Wxl + (size_t)(bn * 128 + srow) * IN_DIM + skq * 32;

    f32x4 acc[4][4];
    #pragma unroll
    for (int i = 0; i < 4; ++i)
        #pragma unroll
        for (int j = 0; j < 4; ++j)
            acc[i][j] = (f32x4){0.f, 0.f, 0.f, 0.f};

    uint4 rA0[4], rA1[4], rB0[4], rB1[4];
    #pragma unroll
    for (int j = 0; j < 4; ++j) {
        rA0[j] = *(const uint4*)(gAh + j * 8);
        rA1[j] = *(const uint4*)(gAl + j * 8);
        rB0[j] = *(const uint4*)(gBh + j * 8);
        rB1[j] = *(const uint4*)(gBl + j * 8);
    }

    for (int kc = 0; kc < IN_DIM / 64; ++kc) {
        __syncthreads();
        #pragma unroll
        for (int j = 0; j < 4; ++j) {
            *(uint4*)&Ah[srow * 72 + skq * 32 + j * 8] = rA0[j];
            *(uint4*)&Al[srow * 72 + skq * 32 + j * 8] = rA1[j];
            *(uint4*)&Bh[srow * 72 + skq * 32 + j * 8] = rB0[j];
            *(uint4*)&Bl[srow * 72 + skq * 32 + j * 8] = rB1[j];
        }
        __syncthreads();
        if (kc + 1 < IN_DIM / 64) {
            const int kt = (kc + 1) * 64;
            #pragma unroll
            for (int j = 0; j < 4; ++j) {
                rA0[j] = *(const uint4*)(gAh + kt + j * 8);
                rA1[j] = *(const uint4*)(gAl + kt + j * 8);
                rB0[j] = *(const uint4*)(gBh + kt + j * 8);
                rB1[j] = *(const uint4*)(gBl + kt + j * 8);
            }
        }
        const int g = lane >> 4;
        #pragma unroll
        for (int s = 0; s < 2; ++s) {
            bf16x8 fah[4], fal[4], fbh[4], fbl[4];
            #pragma unroll
            for (int mi = 0; mi < 4; ++mi) {
                int o = (wm * 64 + mi * 16 + (lane & 15)) * 72 + s * 32 + g * 8;
                fah[mi] = *(const bf16x8*)&Ah[o];
                fal[mi] = *(const bf16x8*)&Al[o];
            }
            #pragma unroll
            for (int ni = 0; ni < 4; ++ni) {
                int o = (wn * 64 + ni * 16 + (lane & 15)) * 72 + s * 32 + g * 8;
                fbh[ni] = *(const bf16x8*)&Bh[o];
                fbl[ni] = *(const bf16x8*)&Bl[o];
            }
            #pragma unroll
            for (int mi = 0; mi < 4; ++mi)
                #pragma unroll
                for (int ni = 0; ni < 4; ++ni) {
                    acc[mi][ni] = __builtin_amdgcn_mfma_f32_16x16x32_bf16(fah[mi], fbh[ni], acc[mi][ni], 0, 0, 0);
                    acc[mi][ni] = __builtin_amdgcn_mfma_f32_16x16x32_bf16(fah[mi], fbl[ni], acc[mi][ni], 0, 0, 0);
                    acc[mi][ni] = __builtin_amdgcn_mfma_f32_16x16x32_bf16(fal[mi], fbh[ni], acc[mi][ni], 0, 0, 0);
                }
        }
    }

    // ---- epilogue: LDS transpose -> coalesced float4 row writes ----
    __syncthreads();
    float* Cs = (float*)smem;   // [128][132] = 67584 B, aliases staging LDS
    const int r4 = (lane >> 4) * 4;
    #pragma unroll
    for (int mi = 0; mi < 4; ++mi)
        #pragma unroll
        for (int ni = 0; ni < 4; ++ni) {
            const int col = wn * 64 + ni * 16 + (lane & 15);
            const int row = wm * 64 + mi * 16 + r4;
            #pragma unroll
            for (int r = 0; r < 4; ++r)
                Cs[(row + r) * 132 + col] = acc[mi][ni][r];
        }
    __syncthreads();
    const int t0 = bm * 128, c0 = bn * 128;
    #pragma unroll
    for (int i = 0; i < 16; ++i) {
        int row = i * 8 + (tid >> 5);
        float4 v = *(const float4*)&Cs[row * 132 + (tid & 31) * 4];
        *(float4*)&Hbuf[(size_t)(t0 + row) * R5 + c0 + (tid & 31) * 4] = v;
    }
}

// ---------------------------------------------------------------------------
// Kernel 4 (per level): Hbuf[t][1024+r] += Wh_r . h[parent(t)], coalesced RMW.
// ---------------------------------------------------------------------------
__global__ __launch_bounds__(256)
void hgemm_mfma(int lvl,
                const int* __restrict__ level_start,
                const int* __restrict__ level_nodes,
                const int* __restrict__ parent_pos,
                const ushort* __restrict__ hh, const ushort* __restrict__ hl,
                const ushort* __restrict__ Whh, const ushort* __restrict__ Whl,
                const ushort* __restrict__ zpad,
                float* __restrict__ Hbuf)
{
    const int s0 = level_start[lvl];
    const int n  = level_start[lvl + 1] - s0;
    const int bm = blockIdx.y;
    if (bm * 64 >= n) return;
    const int bn = blockIdx.x;
    const int tid = threadIdx.x;
    const int lane = tid & 63;
    const int wid = tid >> 6;
    const int wm = wid & 1, wn = wid >> 1;

    __shared__ __align__(16) ushort smem[384 * 72];   // 55296 B
    ushort* Ah = smem;               // 64*72
    ushort* Al = smem + 64 * 72;
    ushort* Bh = smem + 128 * 72;    // 128*72
    ushort* Bl = smem + 256 * 72;
    __shared__ int s_node[64], s_par[64];

    if (tid < 64) {
        int m = bm * 64 + tid;
        if (m < n) {
            int t = level_nodes[s0 + m];
            s_node[tid] = t;
            s_par[tid]  = parent_pos[t];
        } else { s_node[tid] = -1; s_par[tid] = -1; }
    }
    __syncthreads();

    const int arow = tid >> 2, akq = tid & 3;
    const int par = s_par[arow];
    const ushort* gAh = (par >= 0 ? hh + (size_t)par * HID : zpad) + akq * 16;
    const ushort* gAl = (par >= 0 ? hl + (size_t)par * HID : zpad) + akq * 16;
    const int brow = tid >> 1, bkq = tid & 1;
    const ushort* gBh = Whh + (size_t)(bn * 128 + brow) * HID + bkq * 32;
    const ushort* gBl = Whl + (size_t)(bn * 128 + brow) * HID + bkq * 32;

    f32x4 acc[2][4];
    #pragma unroll
    for (int i = 0; i < 2; ++i)
        #pragma unroll
        for (int j = 0; j < 4; ++j)
            acc[i][j] = (f32x4){0.f, 0.f, 0.f, 0.f};

    uint4 rA0[2], rA1[2], rB0[4], rB1[4];
    #pragma unroll
    for (int j = 0; j < 2; ++j) {
        rA0[j] = *(const uint4*)(gAh + j * 8);
        rA1[j] = *(const uint4*)(gAl + j * 8);
    }
    #pragma unroll
    for (int j = 0; j < 4; ++j) {
        rB0[j] = *(const uint4*)(gBh + j * 8);
        rB1[j] = *(const uint4*)(gBl + j * 8);
    }

    for (int kc = 0; kc < HID / 64; ++kc) {
        __syncthreads();
        #pragma unroll
        for (int j = 0; j < 2; ++j) {
            *(uint4*)&Ah[arow * 72 + akq * 16 + j * 8] = rA0[j];
            *(uint4*)&Al[arow * 72 + akq * 16 + j * 8] = rA1[j];
        }
        #pragma unroll
        for (int j = 0; j < 4; ++j) {
            *(uint4*)&Bh[brow * 72 + bkq * 32 + j * 8] = rB0[j];
            *(uint4*)&Bl[brow * 72 + bkq * 32 + j * 8] = rB1[j];
        }
        __syncthreads();
        if (kc + 1 < HID / 64) {
            const int kt = (kc + 1) * 64;
            #pragma unroll
            for (int j = 0; j < 2; ++j) {
                rA0[j] = *(const uint4*)(gAh + kt + j * 8);
                rA1[j] = *(const uint4*)(gAl + kt + j * 8);
            }
            #pragma unroll
            for (int j = 0; j < 4; ++j) {
                rB0[j] = *(const uint4*)(gBh + kt + j * 8);
                rB1[j] = *(const uint4*)(gBl + kt + j * 8);
            }
        }
        const int g = lane >> 4;
        #pragma unroll
        for (int s = 0; s < 2; ++s) {
            bf16x8 fah[2], fal[2], fbh[4], fbl[4];
            #pragma unroll
            for (int mi = 0; mi < 2; ++mi) {
                int o = (wm * 32 + mi * 16 + (lane & 15)) * 72 + s * 32 + g * 8;
                fah[mi] = *(const bf16x8*)&Ah[o];
                fal[mi] = *(const bf16x8*)&Al[o];
            }
            #pragma unroll
            for (int ni = 0; ni < 4; ++ni) {
                int o = (wn * 64 + ni * 16 + (lane & 15)) * 72 + s * 32 + g * 8;
                fbh[ni] = *(const bf16x8*)&Bh[o];
                fbl[ni] = *(const bf16x8*)&Bl[o];
            }
            #pragma unroll
            for (int mi = 0; mi < 2; ++mi)
                #pragma unroll
                for (int ni = 0; ni < 4; ++ni) {
                    acc[mi][ni] = __builtin_amdgcn_mfma_f32_16x16x32_bf16(fah[mi], fbh[ni], acc[mi][ni], 0, 0, 0);
                    acc[mi][ni] = __builtin_amdgcn_mfma_f32_16x16x32_bf16(fah[mi], fbl[ni], acc[mi][ni], 0, 0, 0);
                    acc[mi][ni] = __builtin_amdgcn_mfma_f32_16x16x32_bf16(fal[mi], fbh[ni], acc[mi][ni], 0, 0, 0);
                }
        }
    }

    // ---- epilogue: LDS transpose -> coalesced float4 RMW ----
    __syncthreads();
    float* Cs = (float*)smem;   // [64][132] = 33792 B
    const int r4 = (lane >> 4) * 4;
    #pragma unroll
    for (int mi = 0; mi < 2; ++mi)
        #pragma unroll
        for (int ni = 0; ni < 4; ++ni) {
            const int col = wn * 64 + ni * 16 + (lane & 15);
            const int row = wm * 32 + mi * 16 + r4;
            #pragma unroll
            for (int r = 0; r < 4; ++r)
                Cs[(row + r) * 132 + col] = acc[mi][ni][r];
        }
    __syncthreads();
    #pragma unroll
    for (int i = 0; i < 8; ++i) {
        int row = i * 8 + (tid >> 5);
        if (bm * 64 + row < n) {
            int t = s_node[row];
            float* dst = Hbuf + (size_t)t * R5 + HID + bn * 128 + (tid & 31) * 4;
            float4 o = *(const float4*)dst;
            const float* cp = &Cs[row * 132 + (tid & 31) * 4];
            o.x += cp[0]; o.y += cp[1]; o.z += cp[2]; o.w += cp[3];
            *(float4*)dst = o;
        }
    }
}

// ---------------------------------------------------------------------------
// Kernel 5 (per level): elementwise gates + cell update; emits split-bf16 h.
// No barriers, grid-stride over level nodes.
// ---------------------------------------------------------------------------
__global__ __launch_bounds__(256)
void gates_h(int lvl,
             const int* __restrict__ level_start,
             const int* __restrict__ level_nodes,
             const int* __restrict__ parent_pos,
             const float* __restrict__ Hbuf,
             const float* __restrict__ Xemb,
             const int* __restrict__ eidx_all,
             ushort* __restrict__ hh, ushort* __restrict__ hl,
             float* __restrict__ c_all)
{
    const int s0 = level_start[lvl];
    const int n  = level_start[lvl + 1] - s0;
    const int tid = threadIdx.x;

    for (int slot = blockIdx.x; slot < n; slot += gridDim.x) {
        const int t = level_nodes[s0 + slot];
        const int pid = parent_pos[t];
        const int eidx = (pid < 0) ? 0 : eidx_all[pid];

        const float4* H4 = (const float4*)(Hbuf + (size_t)t * R5);
        const float4* E4 = (const float4*)(Xemb + (size_t)eidx * R5);

        float4 Hpx = H4[tid],        Epx = E4[tid];
        float4 Hi  = H4[256 + tid],  Ei  = E4[256 + tid];
        float4 Ho  = H4[512 + tid],  Eo  = E4[512 + tid];
        float4 Hu  = H4[768 + tid],  Eu  = E4[768 + tid];
        float4 Hf  = H4[1024 + tid], Ef  = E4[1024 + tid];
        float4 PC = (pid < 0) ? make_float4(0.f, 0.f, 0.f, 0.f)
                              : ((const float4*)(c_all + (size_t)pid * HID))[tid];

        float cv[4], hv[4];
#define GATE(CP, IDX) { \
        float pxv = Hpx.CP + Epx.CP; \
        float iv  = Hi.CP + Ei.CP; \
        float ov  = Ho.CP + Eo.CP; \
        float uv  = Hu.CP + Eu.CP; \
        float fv  = Hf.CP + Ef.CP; \
        float ig = sigf(iv), og = sigf(ov), ug = tanhf(uv), fg = sigf(fv); \
        float cc = ig * ug + fg * PC.CP; \
        cv[IDX] = cc; \
        hv[IDX] = og * tanhf(cc) * sigf(pxv); }
        GATE(x, 0) GATE(y, 1) GATE(z, 2) GATE(w, 3)
#undef GATE

        ((float4*)(c_all + (size_t)t * HID))[tid] = make_float4(cv[0], cv[1], cv[2], cv[3]);
        ushort4 shi, slo;
        split2(hv[0], shi.x, slo.x); split2(hv[1], shi.y, slo.y);
        split2(hv[2], shi.z, slo.z); split2(hv[3], shi.w, slo.w);
        *(ushort4*)(hh + (size_t)t * HID + (tid << 2)) = shi;
        *(ushort4*)(hl + (size_t)t * HID + (tid << 2)) = slo;
    }
}

// ---------------------------------------------------------------------------
// Kernel 6 (per level): dists = W_out @ h + b_out for all level nodes (MFMA),
// plus argmax (cols 1..150, first-index tie-break) and commitment write.
// Block = 32 nodes x 160 cols, 4 waves.
// ---------------------------------------------------------------------------
__global__ __launch_bounds__(256)
void dist_mfma(int lvl,
               const int* __restrict__ level_start,
               const int* __restrict__ level_nodes,
               const int* __restrict__ proc_order,
               const ushort* __restrict__ hh, const ushort* __restrict__ hl,
               const ushort* __restrict__ Woh, const ushort* __restrict__ Wol,
               const float* __restrict__ b_out,
               const ushort* __restrict__ zpad,
               int* __restrict__ eidx_all,
               float* __restrict__ out)
{
    const int s0 = level_start[lvl];
    const int n  = level_start[lvl + 1] - s0;
    const int bm = blockIdx.x;
    if (bm * 32 >= n) return;
    const int tid = threadIdx.x;
    const int lane = tid & 63;
    const int wid = tid >> 6;
    const int wm = wid & 1, wn = wid >> 1;

    __shared__ __align__(16) ushort smem[384 * 72];   // 55296 B
    ushort* Ah = smem;              // 32*72
    ushort* Al = smem + 32 * 72;
    ushort* Bh = smem + 64 * 72;    // 160*72
    ushort* Bl = smem + 224 * 72;
    __shared__ int s_node[32];

    if (tid < 32) {
        int m = bm * 32 + tid;
        s_node[tid] = (m < n) ? level_nodes[s0 + m] : -1;
    }
    __syncthreads();

    const int arow = tid >> 3, apc = (tid & 7) * 8;
    const int ta = s_node[arow];
    const ushort* gAh = (ta >= 0 ? hh + (size_t)ta * HID : zpad) + apc;
    const ushort* gAl = (ta >= 0 ? hl + (size_t)ta * HID : zpad) + apc;

    f32x4 acc[5];
    #pragma unroll
    for (int f = 0; f < 5; ++f) acc[f] = (f32x4){0.f, 0.f, 0.f, 0.f};

    uint4 rA0, rA1, rB0[5], rB1[5];
    rA0 = *(const uint4*)gAh;
    rA1 = *(const uint4*)gAl;
    #pragma unroll
    for (int j = 0; j < 5; ++j) {
        int i = tid + j * 256;
        int brow = i >> 3, bpc = (i & 7) * 8;
        rB0[j] = *(const uint4*)(Woh + (size_t)brow * HID + bpc);
        rB1[j] = *(const uint4*)(Wol + (size_t)brow * HID + bpc);
    }

    for (int kc = 0; kc < HID / 64; ++kc) {
        __syncthreads();
        *(uint4*)&Ah[arow * 72 + apc] = rA0;
        *(uint4*)&Al[arow * 72 + apc] = rA1;
        #pragma unroll
        for (int j = 0; j < 5; ++j) {
            int i = tid + j * 256;
            int brow = i >> 3, bpc = (i & 7) * 8;
            *(uint4*)&Bh[brow * 72 + bpc] = rB0[j];
            *(uint4*)&Bl[brow * 72 + bpc] = rB1[j];
        }
        __syncthreads();
        if (kc + 1 < HID / 64) {
            const int kt = (kc + 1) * 64;
            rA0 = *(const uint4*)(gAh + kt);
            rA1 = *(const uint4*)(gAl + kt);
            #pragma unroll
            for (int j = 0; j < 5; ++j) {
                int i = tid + j * 256;
                int brow = i >> 3, bpc = (i & 7) * 8;
                rB0[j] = *(const uint4*)(Woh + (size_t)brow * HID + kt + bpc);
                rB1[j] = *(const uint4*)(Wol + (size_t)brow * HID + kt + bpc);
            }
        }
        const int g = lane >> 4;
        #pragma unroll
        for (int s = 0; s < 2; ++s) {
            int ao = (wm * 16 + (lane & 15)) * 72 + s * 32 + g * 8;
            bf16x8 fah = *(const bf16x8*)&Ah[ao];
            bf16x8 fal = *(const bf16x8*)&Al[ao];
            #pragma unroll
            for (int f = 0; f < 5; ++f) {
                int bo = (wn * 80 + f * 16 + (lane & 15)) * 72 + s * 32 + g * 8;
                bf16x8 fbh = *(const bf16x8*)&Bh[bo];
                bf16x8 fbl = *(const bf16x8*)&Bl[bo];
                acc[f] = __builtin_amdgcn_mfma_f32_16x16x32_bf16(fah, fbh, acc[f], 0, 0, 0);
                acc[f] = __builtin_amdgcn_mfma_f32_16x16x32_bf16(fah, fbl, acc[f], 0, 0, 0);
                acc[f] = __builtin_amdgcn_mfma_f32_16x16x32_bf16(fal, fbh, acc[f], 0, 0, 0);
            }
        }
    }

    __syncthreads();
    float* ds = (float*)smem;   // [32][172] = 22016 B
    const int r4 = (lane >> 4) * 4;
    #pragma unroll
    for (int f = 0; f < 5; ++f) {
        const int col = wn * 80 + f * 16 + (lane & 15);
        const int row = wm * 16 + r4;
        #pragma unroll
        for (int r = 0; r < 4; ++r)
            ds[(row + r) * 172 + col] = acc[f][r];
    }
    __syncthreads();

    const int m = tid >> 3, sub = tid & 7;
    float bv = -3.4e38f; int bc = NCLS;
    const bool live = (bm * 32 + m < n);
    if (live) {
        const int t = s_node[m];
        const int node = proc_order[t];
        float* drow = out + (size_t)node * NCLS;
        for (int c = sub; c < NCLS; c += 8) {
            float v = ds[m * 172 + c] + b_out[c];
            drow[c] = v;
            if (c >= 1 && (v > bv || (v == bv && c < bc))) { bv = v; bc = c; }
        }
        #pragma unroll
        for (int off = 4; off > 0; off >>= 1) {
            float ov = __shfl_down(bv, off, 64);
            int   oc = __shfl_down(bc, off, 64);
            if (ov > bv || (ov == bv && oc < bc)) { bv = ov; bc = oc; }
        }
        if (sub == 0) {
            eidx_all[t] = bc + 1;
            out[(size_t)N_OBJ * NCLS + node] = (float)bc;
        }
    }
}

// ---------------------------------------------------------------------------
extern "C" void kernel_launch(void* const* d_in, const int* in_sizes, int n_in,
                              void* d_out, int out_size, void* d_ws, size_t ws_size,
                              hipStream_t stream)
{
    const float* features = (const float*)d_in[0];
    const float* embed_W  = (const float*)d_in[1];
    const float* W_px     = (const float*)d_in[2];
    const float* b_px     = (const float*)d_in[3];
    const float* W_ioux   = (const float*)d_in[4];
    const float* b_ioux   = (const float*)d_in[5];
    const float* W_iouh   = (const float*)d_in[6];
    const float* b_iouh   = (const float*)d_in[7];
    const float* W_fx     = (const float*)d_in[8];
    const float* b_fx     = (const float*)d_in[9];
    const float* W_fh     = (const float*)d_in[10];
    const float* b_fh     = (const float*)d_in[11];
    const float* W_out    = (const float*)d_in[12];
    const float* b_out    = (const float*)d_in[13];
    const int* proc_order = (const int*)d_in[14];
    const int* parent_pos = (const int*)d_in[15];
    float* out = (float*)d_out;

    // workspace layout (~176 MB)
    float* Hbuf  = (float*)d_ws;                          // [N_OBJ][R5]
    float* c_all = Hbuf + (size_t)N_OBJ * R5;             // [N_OBJ][HID]
    float* Xemb  = c_all + (size_t)N_OBJ * HID;           // [NEMB][R5]
    ushort* Whh = (ushort*)(Xemb + (size_t)NEMB * R5);    // [RH][HID]
    ushort* Whl = Whh + (size_t)RH * HID;
    ushort* Wxh = Whl + (size_t)RH * HID;                 // [R5][IN_DIM]
    ushort* Wxl = Wxh + (size_t)R5 * IN_DIM;
    ushort* Fh  = Wxl + (size_t)R5 * IN_DIM;              // [N_OBJ][IN_DIM]
    ushort* Fl  = Fh + (size_t)N_OBJ * IN_DIM;
    ushort* hh  = Fl + (size_t)N_OBJ * IN_DIM;            // [N_OBJ][HID]
    ushort* hl  = hh + (size_t)N_OBJ * HID;
    ushort* Woh = hl + (size_t)N_OBJ * HID;               // [NCPAD][HID]
    ushort* Wol = Woh + (size_t)NCPAD * HID;
    ushort* zpad = Wol + (size_t)NCPAD * HID;             // [1024] zeros
    int* eidx_all    = (int*)(zpad + 1024);
    int* level_nodes = eidx_all + N_OBJ;
    int* level_start = level_nodes + N_OBJ;

    build_levels<<<1, 1024, 0, stream>>>(parent_pos, level_nodes, level_start, zpad);
    xemb_kernel<<<dim3(NEMB, R5 / 256), 256, 0, stream>>>(
        embed_W, W_px, W_ioux, W_fx, b_px, b_ioux, b_iouh, b_fx, b_fh, Xemb);
    convert_wh<<<RH * HID / 1024, 256, 0, stream>>>(W_iouh, W_fh, Whh, Whl);
    convert_wx<<<R5 * IN_DIM / 1024, 256, 0, stream>>>(W_px, W_ioux, W_fx, Wxh, Wxl);
    convert_f<<<N_OBJ * IN_DIM / 1024, 256, 0, stream>>>(features, proc_order, Fh, Fl);
    convert_wout<<<NCPAD * HID / 1024, 256, 0, stream>>>(W_out, Woh, Wol);

    xgemm_mfma<<<(N_OBJ / 128) * (R5 / 128), 256, 0, stream>>>(Fh, Fl, Wxh, Wxl, Hbuf);

    gates_h<<<512, 256, 0, stream>>>(
        0, level_start, level_nodes, parent_pos, Hbuf, Xemb, eidx_all, hh, hl, c_all);
    dist_mfma<<<N_OBJ / 32, 256, 0, stream>>>(
        0, level_start, level_nodes, proc_order, hh, hl, Woh, Wol, b_out, zpad,
        eidx_all, out);

    for (int l = 1; l < MAXLVL; ++l) {
        hgemm_mfma<<<dim3(RH / 128, N_OBJ / 64), 256, 0, stream>>>(
            l, level_start, level_nodes, parent_pos, hh, hl, Whh, Whl, zpad, Hbuf);
        gates_h<<<512, 256, 0, stream>>>(
            l, level_start, level_nodes, parent_pos, Hbuf, Xemb, eidx_all, hh, hl, c_all);
        dist_mfma<<<N_OBJ / 32, 256, 0, stream>>>(
            l, level_start, level_nodes, proc_order, hh, hl, Woh, Wol, b_out, zpad,
            eidx_all, out);
    }
}